// Round 1
// baseline (777.067 us; speedup 1.0000x reference)
//
#include <hip/hip_runtime.h>
#include <stdint.h>

#define FH 512
#define FW 768
#define HWSZ (FH*FW)           // 393216
#define NA 12
#define NANCH (HWSZ*NA)        // 4718592
#define KSEL 6000
#define NWORDS 94              // ceil(6000/64)
#define NPAD (NWORDS*64)       // 6016
#define POSTN 300
#define TIECAP 4096

// 12 base anchors (ratios 0.5,1,2 x scales 4,8,16,32), precomputed from the
// reference generate_anchors(16,(0.5,1,2),(4,8,16,32)).
__constant__ float c_anch[12][4] = {
  {-38.f,-16.f,53.f,31.f},{-84.f,-40.f,99.f,55.f},{-176.f,-88.f,191.f,103.f},{-360.f,-184.f,375.f,199.f},
  {-24.f,-24.f,39.f,39.f},{-56.f,-56.f,71.f,71.f},{-120.f,-120.f,135.f,135.f},{-248.f,-248.f,263.f,263.f},
  {-14.f,-36.f,29.f,51.f},{-36.f,-80.f,51.f,95.f},{-80.f,-168.f,95.f,183.f},{-168.f,-344.f,183.f,359.f}
};

__device__ __forceinline__ uint32_t fsort(float f){
  uint32_t b = __float_as_uint(f);
  return (b & 0x80000000u) ? ~b : (b | 0x80000000u);
}
__device__ __forceinline__ float funsort(uint32_t u){
  uint32_t b = (u & 0x80000000u) ? (u & 0x7fffffffu) : ~u;
  return __uint_as_float(b);
}

// Compute clipped proposal box for anchor a at location loc. Plain (non-fma)
// fp32 to match XLA's uncontracted elementwise lowering.
__device__ __forceinline__ float4 prop_box(int a, int loc, const float* __restrict__ bbox,
                                           float wlim, float hlim){
#pragma clang fp contract(off)
  int hh = loc / FW;
  int ww = loc - hh * FW;
  float sx = (float)ww * 16.0f, sy = (float)hh * 16.0f;
  float x1a = c_anch[a][0] + sx, y1a = c_anch[a][1] + sy;
  float x2a = c_anch[a][2] + sx, y2a = c_anch[a][3] + sy;
  float wa = x2a - x1a + 1.0f, ha = y2a - y1a + 1.0f;
  float cxa = x1a + 0.5f * wa, cya = y1a + 0.5f * ha;
  size_t base = (size_t)(4*a) * HWSZ + (size_t)loc;
  float d0 = bbox[base];
  float d1 = bbox[base + (size_t)HWSZ];
  float d2 = bbox[base + (size_t)2*HWSZ];
  float d3 = bbox[base + (size_t)3*HWSZ];
  float pcx = d0 * wa + cxa;
  float pcy = d1 * ha + cya;
  float pw  = expf(d2) * wa;
  float ph  = expf(d3) * ha;
  float x1 = pcx - 0.5f * pw, y1 = pcy - 0.5f * ph;
  float x2 = pcx + 0.5f * pw, y2 = pcy + 0.5f * ph;
  x1 = fminf(fmaxf(x1, 0.0f), wlim);
  y1 = fminf(fmaxf(y1, 0.0f), hlim);
  x2 = fminf(fmaxf(x2, 0.0f), wlim);
  y2 = fminf(fmaxf(y2, 0.0f), hlim);
  return make_float4(x1, y1, x2, y2);
}

// state words: 0=prefix/T 1=krem 2=selCount(>T) 3=tieCount 4=keepCount
__global__ void k_init(uint32_t* __restrict__ state, uint32_t* __restrict__ hist){
  int t = threadIdx.x;
  hist[t] = 0;               // 1024 = 4 passes x 256 bins
  if (t < 8) state[t] = (t == 1) ? (uint32_t)KSEL : 0u;
}

// Score + validity + sortable key, u stored in (a, loc) layout (all coalesced).
// Fused histogram pass 0 (top 8 bits).
__global__ void k_score(const float* __restrict__ cls, const float* __restrict__ bbox,
                        const float* __restrict__ iminfo,
                        uint32_t* __restrict__ u2, uint32_t* __restrict__ hist0){
  __shared__ uint32_t lh[256];
  lh[threadIdx.x] = 0;
  __syncthreads();
  int p = blockIdx.x * 256 + threadIdx.x;
  float him = iminfo[0], wim = iminfo[1], scale = iminfo[2];
  float ms = 16.0f * scale - 1.0f;
  int a = p / HWSZ;
  int loc = p - a * HWSZ;
  float4 bx = prop_box(a, loc, bbox, wim - 1.0f, him - 1.0f);
  bool valid = (bx.z - bx.x >= ms) && (bx.w - bx.y >= ms);
  float sc = cls[(size_t)(NA + a) * HWSZ + loc];
  float m = valid ? sc : -1e30f;
  uint32_t u = fsort(m);
  u2[p] = u;
  atomicAdd(&lh[u >> 24], 1u);
  __syncthreads();
  uint32_t v = lh[threadIdx.x];
  if (v) atomicAdd(&hist0[threadIdx.x], v);
}

__global__ void k_hist(const uint32_t* __restrict__ u2, const uint32_t* __restrict__ state,
                       uint32_t* __restrict__ hist, int shift){
  __shared__ uint32_t lh[256];
  lh[threadIdx.x] = 0;
  __syncthreads();
  uint32_t prefix = state[0];
  int stride = gridDim.x * 256;
  for (int p = blockIdx.x * 256 + threadIdx.x; p < NANCH; p += stride){
    uint32_t u = u2[p];
    if (((u ^ prefix) >> (shift + 8)) == 0)
      atomicAdd(&lh[(u >> shift) & 255u], 1u);
  }
  __syncthreads();
  uint32_t v = lh[threadIdx.x];
  if (v) atomicAdd(&hist[threadIdx.x], v);
}

__global__ void k_scan(const uint32_t* __restrict__ hist, uint32_t* __restrict__ state, int shift){
  __shared__ uint32_t h[256];
  int t = threadIdx.x;
  h[t] = hist[t];
  uint32_t k = state[1];
  __syncthreads();
  uint32_t cg = 0;
  for (int b = t + 1; b < 256; ++b) cg += h[b];
  if (cg < k && cg + h[t] >= k){
    state[0] = state[0] | (((uint32_t)t) << shift);
    state[1] = k - cg;
  }
}

__global__ void k_compact(const uint32_t* __restrict__ u2, uint32_t* __restrict__ state,
                          uint32_t* __restrict__ sel_u, uint32_t* __restrict__ sel_idx,
                          uint32_t* __restrict__ tie){
  uint32_t T = state[0];
  int stride = gridDim.x * 256;
  for (int p = blockIdx.x * 256 + threadIdx.x; p < NANCH; p += stride){
    uint32_t u = u2[p];
    if (u >= T){
      int a = p / HWSZ;
      int loc = p - a * HWSZ;
      uint32_t n = (uint32_t)loc * NA + (uint32_t)a;
      if (u > T){
        uint32_t pos = atomicAdd(&state[2], 1u);
        if (pos < (uint32_t)NPAD){ sel_u[pos] = u; sel_idx[pos] = n; }
      } else {
        uint32_t pos = atomicAdd(&state[3], 1u);
        if (pos < (uint32_t)TIECAP) tie[pos] = n;
      }
    }
  }
}

// Sort ties ascending by original index, append the needed k_rem of them.
__global__ void k_fin(uint32_t* __restrict__ state, uint32_t* __restrict__ sel_u,
                      uint32_t* __restrict__ sel_idx, const uint32_t* __restrict__ tie){
  __shared__ uint32_t tl[TIECAP];
  uint32_t tieCount = state[3]; if (tieCount > TIECAP) tieCount = TIECAP;
  uint32_t krem = state[1];
  uint32_t base = state[2]; if (base > KSEL) base = KSEL;
  uint32_t T = state[0];
  for (int i = threadIdx.x; i < TIECAP; i += 1024)
    tl[i] = (i < (int)tieCount) ? tie[i] : 0xFFFFFFFFu;
  __syncthreads();
  for (int kk = 2; kk <= TIECAP; kk <<= 1){
    for (int j = kk >> 1; j > 0; j >>= 1){
      for (int i = threadIdx.x; i < TIECAP; i += 1024){
        int ixj = i ^ j;
        if (ixj > i){
          uint32_t x = tl[i], y = tl[ixj];
          bool up = ((i & kk) == 0);
          if ((x > y) == up){ tl[i] = y; tl[ixj] = x; }
        }
      }
      __syncthreads();
    }
  }
  uint32_t take = krem < tieCount ? krem : tieCount;
  if (base + take > KSEL) take = KSEL - base;
  for (uint32_t t = threadIdx.x; t < take; t += 1024){
    sel_u[base + t] = T;
    sel_idx[base + t] = tl[t];
  }
  // deterministic fill (pathological-only)
  for (uint32_t t = base + take + threadIdx.x; t < KSEL; t += 1024){
    sel_u[t] = 0u; sel_idx[t] = 0x7FFFFFFFu - t;
  }
}

// Rank each of 6000 by unique 64-bit key (score desc, index asc), scatter into
// sorted order; recompute box for the epilogue.
__global__ __launch_bounds__(256) void k_rank(const uint32_t* __restrict__ sel_u,
                       const uint32_t* __restrict__ sel_idx,
                       const float* __restrict__ bbox, const float* __restrict__ iminfo,
                       uint32_t* __restrict__ sorted_idx, float* __restrict__ sorted_sc,
                       float4* __restrict__ boxes){
  __shared__ uint64_t keys[KSEL];
  for (int j = threadIdx.x; j < KSEL; j += 256)
    keys[j] = (((uint64_t)sel_u[j]) << 32) | (uint32_t)(~sel_idx[j]);
  __syncthreads();
  int e = blockIdx.x * 256 + threadIdx.x;
  if (e >= KSEL) return;
  uint64_t myk = keys[e];
  int r = 0;
  for (int j = 0; j < KSEL; j += 8){
    r += (int)(keys[j]   > myk) + (int)(keys[j+1] > myk)
       + (int)(keys[j+2] > myk) + (int)(keys[j+3] > myk)
       + (int)(keys[j+4] > myk) + (int)(keys[j+5] > myk)
       + (int)(keys[j+6] > myk) + (int)(keys[j+7] > myk);
  }
  uint32_t idx = ~(uint32_t)myk;
  uint32_t u = (uint32_t)(myk >> 32);
  sorted_idx[r] = idx;
  sorted_sc[r] = funsort(u);
  int a = (int)(idx % NA);
  int loc = (int)(idx / NA);
  float him = iminfo[0], wim = iminfo[1];
  boxes[r] = prop_box(a, loc, bbox, wim - 1.0f, him - 1.0f);
}

// Suppression bit matrix, transposed layout mask[colgroup][row] for coalesced
// writes. Bit jj set in word (i, cg) iff IoU(box_i, box_{cg*64+jj}) > 0.7.
__global__ void k_mask(const float4* __restrict__ boxes, uint64_t* __restrict__ mask){
#pragma clang fp contract(off)
  int tid = threadIdx.x;
  int cg = blockIdx.x, rg = blockIdx.y;
  __shared__ float4 cb[64];
  int c0 = cg * 64;
  int cj = c0 + tid;
  cb[tid] = (cj < KSEL) ? boxes[cj] : make_float4(0.f, 0.f, 0.f, 0.f);
  __syncthreads();
  int i = rg * 64 + tid;
  uint64_t m = 0;
  if (i < KSEL){
    float4 bi = boxes[i];
    float zx = bi.z + 1.0f, zy = bi.w + 1.0f;
    float ai = (zx - bi.x) * (zy - bi.y);
    int jmax = KSEL - c0; if (jmax > 64) jmax = 64;
    for (int jj = 0; jj < jmax; ++jj){
      int j = c0 + jj;
      if (j == i) continue;
      float4 bj = cb[jj];
      float jx = bj.z + 1.0f, jy = bj.w + 1.0f;
      float ww = fminf(zx, jx) - fmaxf(bi.x, bj.x); ww = fmaxf(ww, 0.0f);
      float hh = fminf(zy, jy) - fmaxf(bi.y, bj.y); hh = fmaxf(hh, 0.0f);
      float inter = ww * hh;
      float aj = (jx - bj.x) * (jy - bj.y);
      float iou = inter / (ai + aj - inter);
      if (iou > 0.7f) m |= (1ull << jj);
    }
  }
  mask[(size_t)cg * NPAD + (size_t)(rg * 64 + tid)] = m;
}

// Single-wave sequential greedy scan with bit-skipping + early exit at 300 kept.
__global__ void k_nms(const uint64_t* __restrict__ mask, uint32_t* __restrict__ state,
                      uint32_t* __restrict__ keepList){
  __shared__ uint64_t sup[NWORDS];
  int l = threadIdx.x;
  for (int w = l; w < NWORDS; w += 64) sup[w] = 0ull;
  __syncthreads();
  int cnt = 0;
  for (int c = 0; c < NWORDS; ++c){
    uint64_t validm = (c == NWORDS - 1) ? ((1ull << (KSEL - 64*(NWORDS-1))) - 1ull) : ~0ull;
    uint64_t avail = (~sup[c]) & validm;
    while (avail){
      int b = __ffsll((long long)avail) - 1;
      int i = c * 64 + b;
      if (l == 0) keepList[cnt] = (uint32_t)i;
      ++cnt;
      if (cnt >= POSTN){ if (l == 0) state[4] = (uint32_t)cnt; return; }
      for (int w = l; w < NWORDS; w += 64)
        sup[w] |= mask[(size_t)w * NPAD + (size_t)i];
      __syncthreads();
      uint64_t below = (b == 63) ? ~0ull : ((2ull << b) - 1ull);
      avail = (~sup[c]) & validm & ~below;
    }
  }
  if (l == 0) state[4] = (uint32_t)cnt;
}

__global__ void k_out(const uint32_t* __restrict__ state, const uint32_t* __restrict__ keepList,
                      const float4* __restrict__ boxes, const float* __restrict__ sorted_sc,
                      float* __restrict__ out){
  int r = blockIdx.x * blockDim.x + threadIdx.x;
  if (r >= POSTN) return;
  uint32_t cnt = state[4];
  float x1 = 0.f, y1 = 0.f, x2 = 0.f, y2 = 0.f, sc = 0.f;
  if (r < (int)cnt){
    int i = (int)keepList[r];
    float4 b = boxes[i];
    x1 = b.x; y1 = b.y; x2 = b.z; y2 = b.w;
    sc = sorted_sc[i];
  }
  out[r*5 + 0] = 0.f; out[r*5 + 1] = x1; out[r*5 + 2] = y1;
  out[r*5 + 3] = x2;  out[r*5 + 4] = y2;
  out[POSTN*5 + r] = sc;
}

extern "C" void kernel_launch(void* const* d_in, const int* in_sizes, int n_in,
                              void* d_out, int out_size, void* d_ws, size_t ws_size,
                              hipStream_t stream) {
  const float* cls    = (const float*)d_in[0];
  const float* bbox   = (const float*)d_in[1];
  const float* iminfo = (const float*)d_in[2];
  float* out = (float*)d_out;
  char* ws = (char*)d_ws;

  // ws layout (all offsets 256B aligned), total ~23.6 MB
  uint32_t* u2         = (uint32_t*)(ws + 0);            // NANCH u32
  uint32_t* state      = (uint32_t*)(ws + 18874368);
  uint32_t* hist       = (uint32_t*)(ws + 18874624);     // 4 x 256 u32
  uint32_t* sel_u      = (uint32_t*)(ws + 18878720);     // NPAD u32
  uint32_t* sel_idx    = (uint32_t*)(ws + 18902784);     // NPAD u32
  uint32_t* tie        = (uint32_t*)(ws + 18926848);     // TIECAP u32
  uint32_t* sorted_idx = (uint32_t*)(ws + 18943232);     // NPAD u32
  float*    sorted_sc  = (float*)   (ws + 18967296);     // NPAD f32
  float4*   boxes      = (float4*)  (ws + 18991360);     // NPAD float4
  uint32_t* keepList   = (uint32_t*)(ws + 19087616);     // POSTN u32
  uint64_t* mask       = (uint64_t*)(ws + 19088896);     // NWORDS x NPAD u64

  k_init<<<dim3(1), dim3(1024), 0, stream>>>(state, hist);
  k_score<<<dim3(NANCH/256), dim3(256), 0, stream>>>(cls, bbox, iminfo, u2, hist);
  k_scan<<<dim3(1), dim3(256), 0, stream>>>(hist, state, 24);
  k_hist<<<dim3(4608), dim3(256), 0, stream>>>(u2, state, hist + 256, 16);
  k_scan<<<dim3(1), dim3(256), 0, stream>>>(hist + 256, state, 16);
  k_hist<<<dim3(4608), dim3(256), 0, stream>>>(u2, state, hist + 512, 8);
  k_scan<<<dim3(1), dim3(256), 0, stream>>>(hist + 512, state, 8);
  k_hist<<<dim3(4608), dim3(256), 0, stream>>>(u2, state, hist + 768, 0);
  k_scan<<<dim3(1), dim3(256), 0, stream>>>(hist + 768, state, 0);
  k_compact<<<dim3(4608), dim3(256), 0, stream>>>(u2, state, sel_u, sel_idx, tie);
  k_fin<<<dim3(1), dim3(1024), 0, stream>>>(state, sel_u, sel_idx, tie);
  k_rank<<<dim3(24), dim3(256), 0, stream>>>(sel_u, sel_idx, bbox, iminfo,
                                             sorted_idx, sorted_sc, boxes);
  k_mask<<<dim3(NWORDS, NWORDS), dim3(64), 0, stream>>>(boxes, mask);
  k_nms<<<dim3(1), dim3(64), 0, stream>>>(mask, state, keepList);
  k_out<<<dim3(1), dim3(512), 0, stream>>>(state, keepList, boxes, sorted_sc, out);
}

// Round 4
// 578.679 us; speedup vs baseline: 1.3428x; 1.3428x over previous
//
#include <hip/hip_runtime.h>
#include <stdint.h>

#define FH 512
#define FW 768
#define HWSZ (FH*FW)           // 393216
#define NA 12
#define NANCH (HWSZ*NA)        // 4718592
#define KSEL 6000
#define NWORDS 94              // ceil(6000/64)
#define NPAD (NWORDS*64)       // 6016
#define POSTN 300
#define TIECAP 4096
#define NMSWIN 16

// 12 base anchors (ratios 0.5,1,2 x scales 4,8,16,32), precomputed from the
// reference generate_anchors(16,(0.5,1,2),(4,8,16,32)).
__constant__ float c_anch[12][4] = {
  {-38.f,-16.f,53.f,31.f},{-84.f,-40.f,99.f,55.f},{-176.f,-88.f,191.f,103.f},{-360.f,-184.f,375.f,199.f},
  {-24.f,-24.f,39.f,39.f},{-56.f,-56.f,71.f,71.f},{-120.f,-120.f,135.f,135.f},{-248.f,-248.f,263.f,263.f},
  {-14.f,-36.f,29.f,51.f},{-36.f,-80.f,51.f,95.f},{-80.f,-168.f,95.f,183.f},{-168.f,-344.f,183.f,359.f}
};

__device__ __forceinline__ uint32_t fsort(float f){
  uint32_t b = __float_as_uint(f);
  return (b & 0x80000000u) ? ~b : (b | 0x80000000u);
}
__device__ __forceinline__ float funsort(uint32_t u){
  uint32_t b = (u & 0x80000000u) ? (u & 0x7fffffffu) : ~u;
  return __uint_as_float(b);
}

// Clipped proposal box from loaded deltas. Plain (non-fma) fp32.
__device__ __forceinline__ float4 box_from(int a, int loc, float d0, float d1,
                                           float d2, float d3, float wlim, float hlim){
#pragma clang fp contract(off)
  int hh = loc / FW;
  int ww = loc - hh * FW;
  float sx = (float)ww * 16.0f, sy = (float)hh * 16.0f;
  float x1a = c_anch[a][0] + sx, y1a = c_anch[a][1] + sy;
  float x2a = c_anch[a][2] + sx, y2a = c_anch[a][3] + sy;
  float wa = x2a - x1a + 1.0f, ha = y2a - y1a + 1.0f;
  float cxa = x1a + 0.5f * wa, cya = y1a + 0.5f * ha;
  float pcx = d0 * wa + cxa;
  float pcy = d1 * ha + cya;
  float pw  = expf(d2) * wa;
  float ph  = expf(d3) * ha;
  float x1 = pcx - 0.5f * pw, y1 = pcy - 0.5f * ph;
  float x2 = pcx + 0.5f * pw, y2 = pcy + 0.5f * ph;
  x1 = fminf(fmaxf(x1, 0.0f), wlim);
  y1 = fminf(fmaxf(y1, 0.0f), hlim);
  x2 = fminf(fmaxf(x2, 0.0f), wlim);
  y2 = fminf(fmaxf(y2, 0.0f), hlim);
  return make_float4(x1, y1, x2, y2);
}

__device__ __forceinline__ float4 prop_box(int a, int loc, const float* __restrict__ bbox,
                                           float wlim, float hlim){
  size_t base = (size_t)(4*a) * HWSZ + (size_t)loc;
  float d0 = bbox[base];
  float d1 = bbox[base + (size_t)HWSZ];
  float d2 = bbox[base + (size_t)2*HWSZ];
  float d3 = bbox[base + (size_t)3*HWSZ];
  return box_from(a, loc, d0, d1, d2, d3, wlim, hlim);
}

// state words: 0=prefix/T 1=krem 2=selCount(>T) 3=tieCount 4=keepCount
__global__ void k_init(uint32_t* __restrict__ state, uint32_t* __restrict__ ghist0,
                       uint32_t* __restrict__ hist123){
  int t = threadIdx.x;
  for (int i = t; i < 64*256; i += 1024) ghist0[i] = 0;
  for (int i = t; i < 3*256; i += 1024) hist123[i] = 0;
  if (t < 8) state[t] = (t == 1) ? (uint32_t)KSEL : 0u;
}

// 4 anchors/thread, float4 loads. Per-wave replicated LDS hist (kills the
// same-address LDS atomic serialization), 64-way replicated global hist
// (kills the L2 same-address atomic hotspot).
__global__ __launch_bounds__(256) void k_score(const float* __restrict__ cls,
                        const float* __restrict__ bbox, const float* __restrict__ iminfo,
                        uint32_t* __restrict__ u2, uint32_t* __restrict__ ghist0){
  __shared__ uint32_t lh[4][256];
  for (int i = threadIdx.x; i < 1024; i += 256) ((uint32_t*)lh)[i] = 0;
  __syncthreads();
  int t = blockIdx.x * 256 + threadIdx.x;
  int p0 = t * 4;
  int a = p0 / HWSZ;                 // HWSZ % 4 == 0, so same a for all 4
  int loc0 = p0 - a * HWSZ;
  float him = iminfo[0], wim = iminfo[1], scale = iminfo[2];
  float ms = 16.0f * scale - 1.0f;
  float wlim = wim - 1.0f, hlim = him - 1.0f;
  size_t base = (size_t)(4*a) * HWSZ + (size_t)loc0;
  float4 d0 = *(const float4*)(bbox + base);
  float4 d1 = *(const float4*)(bbox + base + (size_t)HWSZ);
  float4 d2 = *(const float4*)(bbox + base + (size_t)2*HWSZ);
  float4 d3 = *(const float4*)(bbox + base + (size_t)3*HWSZ);
  float4 sc4 = *(const float4*)(cls + (size_t)(NA + a) * HWSZ + loc0);
  uint32_t u[4];
  const float dd0[4] = {d0.x, d0.y, d0.z, d0.w};
  const float dd1[4] = {d1.x, d1.y, d1.z, d1.w};
  const float dd2[4] = {d2.x, d2.y, d2.z, d2.w};
  const float dd3[4] = {d3.x, d3.y, d3.z, d3.w};
  const float ss[4]  = {sc4.x, sc4.y, sc4.z, sc4.w};
  int w = threadIdx.x >> 6;
#pragma unroll
  for (int j = 0; j < 4; ++j){
    float4 bx = box_from(a, loc0 + j, dd0[j], dd1[j], dd2[j], dd3[j], wlim, hlim);
    bool valid = (bx.z - bx.x >= ms) && (bx.w - bx.y >= ms);
    float m = valid ? ss[j] : -1e30f;
    u[j] = fsort(m);
    atomicAdd(&lh[w][u[j] >> 24], 1u);
  }
  *(uint4*)(u2 + p0) = make_uint4(u[0], u[1], u[2], u[3]);
  __syncthreads();
  int b = threadIdx.x;
  uint32_t v = lh[0][b] + lh[1][b] + lh[2][b] + lh[3][b];
  if (v) atomicAdd(&ghist0[(blockIdx.x & 63) * 256 + b], v);
}

// Prefix-conditional 8-bit histogram, uint4 loads, exact grid (1 uint4/thread).
__global__ __launch_bounds__(256) void k_hist(const uint32_t* __restrict__ u2,
                       const uint32_t* __restrict__ state,
                       uint32_t* __restrict__ hist, int shift){
  __shared__ uint32_t lh[256];
  lh[threadIdx.x] = 0;
  __syncthreads();
  uint32_t prefix = state[0];
  int p4 = blockIdx.x * 256 + threadIdx.x;
  uint4 uu = ((const uint4*)u2)[p4];
  uint32_t us[4] = {uu.x, uu.y, uu.z, uu.w};
#pragma unroll
  for (int j = 0; j < 4; ++j){
    uint32_t u = us[j];
    if (((u ^ prefix) >> (shift + 8)) == 0)
      atomicAdd(&lh[(u >> shift) & 255u], 1u);
  }
  __syncthreads();
  uint32_t v = lh[threadIdx.x];
  if (v) atomicAdd(&hist[threadIdx.x], v);
}

__global__ void k_scan(const uint32_t* __restrict__ hist, uint32_t* __restrict__ state,
                       int shift, int reps){
  __shared__ uint32_t h[256];
  int t = threadIdx.x;
  uint32_t v = 0;
  for (int r = 0; r < reps; ++r) v += hist[r * 256 + t];
  h[t] = v;
  uint32_t k = state[1];
  __syncthreads();
  uint32_t cg = 0;
  for (int b = t + 1; b < 256; ++b) cg += h[b];
  if (cg < k && cg + h[t] >= k){
    state[0] = state[0] | (((uint32_t)t) << shift);
    state[1] = k - cg;
  }
}

__global__ __launch_bounds__(256) void k_compact(const uint32_t* __restrict__ u2,
                          uint32_t* __restrict__ state,
                          uint32_t* __restrict__ sel_u, uint32_t* __restrict__ sel_idx,
                          uint32_t* __restrict__ tie){
  uint32_t T = state[0];
  int p4 = blockIdx.x * 256 + threadIdx.x;
  uint4 uu = ((const uint4*)u2)[p4];
  uint32_t us[4] = {uu.x, uu.y, uu.z, uu.w};
#pragma unroll
  for (int j = 0; j < 4; ++j){
    uint32_t u = us[j];
    if (u >= T){
      int p = p4 * 4 + j;
      int a = p / HWSZ;
      int loc = p - a * HWSZ;
      uint32_t n = (uint32_t)loc * NA + (uint32_t)a;
      if (u > T){
        uint32_t pos = atomicAdd(&state[2], 1u);
        if (pos < (uint32_t)NPAD){ sel_u[pos] = u; sel_idx[pos] = n; }
      } else {
        uint32_t pos = atomicAdd(&state[3], 1u);
        if (pos < (uint32_t)TIECAP) tie[pos] = n;
      }
    }
  }
}

// Sort ties ascending by original index (bitonic over next-pow2(tieCount) only;
// ties are typically 0-2 so this is ~free), append the needed k_rem of them.
__global__ void k_fin(uint32_t* __restrict__ state, uint32_t* __restrict__ sel_u,
                      uint32_t* __restrict__ sel_idx, const uint32_t* __restrict__ tie){
  __shared__ uint32_t tl[TIECAP];
  uint32_t tieCount = state[3]; if (tieCount > TIECAP) tieCount = TIECAP;
  uint32_t krem = state[1];
  uint32_t base = state[2]; if (base > KSEL) base = KSEL;
  uint32_t T = state[0];
  uint32_t m = 1; while (m < tieCount) m <<= 1;
  if (m > TIECAP) m = TIECAP;
  for (uint32_t i = threadIdx.x; i < m; i += 1024)
    tl[i] = (i < tieCount) ? tie[i] : 0xFFFFFFFFu;
  __syncthreads();
  for (uint32_t kk = 2; kk <= m; kk <<= 1){
    for (uint32_t j = kk >> 1; j > 0; j >>= 1){
      for (uint32_t i = threadIdx.x; i < m; i += 1024){
        uint32_t ixj = i ^ j;
        if (ixj > i){
          uint32_t x = tl[i], y = tl[ixj];
          bool up = ((i & kk) == 0);
          if ((x > y) == up){ tl[i] = y; tl[ixj] = x; }
        }
      }
      __syncthreads();
    }
  }
  uint32_t take = krem < tieCount ? krem : tieCount;
  if (base + take > KSEL) take = KSEL - base;
  for (uint32_t t = threadIdx.x; t < take; t += 1024){
    sel_u[base + t] = T;
    sel_idx[base + t] = tl[t];
  }
  // deterministic fill (pathological-only)
  for (uint32_t t = base + take + threadIdx.x; t < KSEL; t += 1024){
    sel_u[t] = 0u; sel_idx[t] = 0x7FFFFFFFu - t;
  }
}

// Rank each of 6000 by unique 64-bit key (score desc, index asc); 4 threads
// per element, b128 LDS reads. Scatter boxes/scores into sorted order.
__global__ __launch_bounds__(256) void k_rank(const uint32_t* __restrict__ sel_u,
                       const uint32_t* __restrict__ sel_idx,
                       const float* __restrict__ bbox, const float* __restrict__ iminfo,
                       float* __restrict__ sorted_sc, float4* __restrict__ boxes){
  __shared__ __align__(16) uint64_t keys[NPAD];
  __shared__ uint32_t part[256];
  for (int j = threadIdx.x; j < NPAD; j += 256)
    keys[j] = (j < KSEL) ? ((((uint64_t)sel_u[j]) << 32) | (uint32_t)(~sel_idx[j])) : 0ull;
  __syncthreads();
  int e = blockIdx.x * 64 + (threadIdx.x & 63);
  int q = threadIdx.x >> 6;
  uint64_t myk = (e < KSEL) ? keys[e] : ~0ull;
  int r = 0;
  int lo = q * (NPAD / 4);
#pragma unroll 2
  for (int j = lo; j < lo + NPAD / 4; j += 8){
    ulonglong2 k0 = *(const ulonglong2*)&keys[j];
    ulonglong2 k1 = *(const ulonglong2*)&keys[j + 2];
    ulonglong2 k2 = *(const ulonglong2*)&keys[j + 4];
    ulonglong2 k3 = *(const ulonglong2*)&keys[j + 6];
    r += (int)(k0.x > myk) + (int)(k0.y > myk) + (int)(k1.x > myk) + (int)(k1.y > myk)
       + (int)(k2.x > myk) + (int)(k2.y > myk) + (int)(k3.x > myk) + (int)(k3.y > myk);
  }
  part[threadIdx.x] = (uint32_t)r;
  __syncthreads();
  if (q == 0 && e < KSEL){
    int t = threadIdx.x;
    int rr = (int)(part[t] + part[t + 64] + part[t + 128] + part[t + 192]);
    uint32_t idx = ~(uint32_t)myk;
    uint32_t u = (uint32_t)(myk >> 32);
    sorted_sc[rr] = funsort(u);
    int a = (int)(idx % NA);
    int loc = (int)(idx / NA);
    boxes[rr] = prop_box(a, loc, bbox, iminfo[1] - 1.0f, iminfo[0] - 1.0f);
  }
}

// Suppression bit matrix, column-major mask[colgroup][row] for coalesced writes.
__global__ void k_mask(const float4* __restrict__ boxes, uint64_t* __restrict__ mask){
#pragma clang fp contract(off)
  int tid = threadIdx.x;
  int cg = blockIdx.x, rg = blockIdx.y;
  __shared__ float4 cb[64];
  int c0 = cg * 64;
  int cj = c0 + tid;
  cb[tid] = (cj < KSEL) ? boxes[cj] : make_float4(0.f, 0.f, 0.f, 0.f);
  __syncthreads();
  int i = rg * 64 + tid;
  uint64_t m = 0;
  if (i < KSEL){
    float4 bi = boxes[i];
    float zx = bi.z + 1.0f, zy = bi.w + 1.0f;
    float ai = (zx - bi.x) * (zy - bi.y);
    int jmax = KSEL - c0; if (jmax > 64) jmax = 64;
    for (int jj = 0; jj < jmax; ++jj){
      int j = c0 + jj;
      if (j == i) continue;
      float4 bj = cb[jj];
      float jx = bj.z + 1.0f, jy = bj.w + 1.0f;
      float ww = fminf(zx, jx) - fmaxf(bi.x, bj.x); ww = fmaxf(ww, 0.0f);
      float hh = fminf(zy, jy) - fmaxf(bi.y, bj.y); hh = fmaxf(hh, 0.0f);
      float inter = ww * hh;
      float aj = (jx - bj.x) * (jy - bj.y);
      float iou = inter / (ai + aj - inter);
      if (iou > 0.7f) m |= (1ull << jj);
    }
  }
  mask[(size_t)cg * NPAD + (size_t)(rg * 64 + tid)] = m;
}

// Speculative-window greedy NMS: find first up-to-16 available indices, gather
// their mask rows in ONE memory round, process from LDS. Sorted-by-score
// neighbors are spatially uncorrelated, so most window members survive ->
// ~K kept per latency round instead of 1. Hard round cap guarantees
// termination on any (even corrupted) mask contents.
__global__ __launch_bounds__(64) void k_nms(const uint64_t* __restrict__ mask,
                      uint32_t* __restrict__ state, uint32_t* __restrict__ keepList){
  __shared__ uint64_t sup[NWORDS];
  __shared__ uint64_t buf[NMSWIN][96];
  __shared__ uint32_t cand[NMSWIN];
  int l = threadIdx.x;
  for (int w = l; w < NWORDS; w += 64) sup[w] = 0ull;
  __syncthreads();
  if (l == 0) sup[NWORDS - 1] = ~((1ull << (KSEL & 63)) - 1ull);  // pad bits suppressed
  __syncthreads();
  int cnt = 0;
  int pos = 0;
  for (int round = 0; round < 512 && cnt < POSTN && pos < KSEL; ++round){
    // availability for this lane's words (word l, word 64+l)
    uint64_t a0 = ~sup[l];
    uint64_t a1 = (l < NWORDS - 64) ? ~sup[64 + l] : 0ull;
    int pw = pos >> 6, pb = pos & 63;
    if (l < pw) a0 = 0ull; else if (l == pw) a0 &= (~0ull << pb);
    if (64 + l < pw) a1 = 0ull; else if (64 + l == pw) a1 &= (~0ull << pb);
    int c0 = __popcll(a0), c1 = __popcll(a1);
    // inclusive prefix over word order 0..93
    int s0 = c0;
#pragma unroll
    for (int off = 1; off < 64; off <<= 1){ int n = __shfl_up(s0, off, 64); if (l >= off) s0 += n; }
    int tot0 = __shfl(s0, 63, 64);
    int s1 = c1;
#pragma unroll
    for (int off = 1; off < 64; off <<= 1){ int n = __shfl_up(s1, off, 64); if (l >= off) s1 += n; }
    int tot1 = __shfl(s1, 63, 64);
    int e0 = s0 - c0;
    int e1 = tot0 + s1 - c1;
    int total = tot0 + tot1;
    int K = total < NMSWIN ? total : NMSWIN;
    if (K == 0) break;
    // extract candidates with global rank < NMSWIN (disjoint slots per lane)
    {
      int need0 = NMSWIN - e0;
      if (need0 > 0 && a0){
        int take = c0 < need0 ? c0 : need0;
        uint64_t mm = a0;
        for (int x = 0; x < take; ++x){
          int b = __ffsll((long long)mm) - 1; mm &= mm - 1;
          cand[e0 + x] = (uint32_t)(l * 64 + b);
        }
      }
      int need1 = NMSWIN - e1;
      if (need1 > 0 && a1){
        int take = c1 < need1 ? c1 : need1;
        uint64_t mm = a1;
        for (int x = 0; x < take; ++x){
          int b = __ffsll((long long)mm) - 1; mm &= mm - 1;
          cand[e1 + x] = (uint32_t)((64 + l) * 64 + b);
        }
      }
    }
    __syncthreads();
    // gather K rows (94 u64 each) in one latency round
    for (int f = l; f < NMSWIN * 96; f += 64){
      int k = f / 96, w = f - k * 96;
      if (k < K && w < NWORDS) buf[k][w] = mask[(size_t)w * NPAD + cand[k]];
    }
    int lastIdx = (int)cand[K - 1];
    __syncthreads();
    for (int k = 0; k < K; ++k){
      uint32_t i = cand[k];
      uint64_t sw = sup[i >> 6];
      if (!((sw >> (i & 63)) & 1ull)){
        if (l == 0) keepList[cnt] = i;
        ++cnt;
        if (cnt >= POSTN) break;
        sup[l] |= buf[k][l];
        if (l < NWORDS - 64) sup[64 + l] |= buf[k][64 + l];
      }
      __syncthreads();
    }
    pos = lastIdx + 1;
  }
  __syncthreads();
  if (l == 0) state[4] = (uint32_t)cnt;
}

__global__ void k_out(const uint32_t* __restrict__ state, const uint32_t* __restrict__ keepList,
                      const float4* __restrict__ boxes, const float* __restrict__ sorted_sc,
                      float* __restrict__ out){
  int r = blockIdx.x * blockDim.x + threadIdx.x;
  if (r >= POSTN) return;
  uint32_t cnt = state[4];
  float x1 = 0.f, y1 = 0.f, x2 = 0.f, y2 = 0.f, sc = 0.f;
  if (r < (int)cnt){
    int i = (int)keepList[r];
    float4 b = boxes[i];
    x1 = b.x; y1 = b.y; x2 = b.z; y2 = b.w;
    sc = sorted_sc[i];
  }
  out[r*5 + 0] = 0.f; out[r*5 + 1] = x1; out[r*5 + 2] = y1;
  out[r*5 + 3] = x2;  out[r*5 + 4] = y2;
  out[POSTN*5 + r] = sc;
}

extern "C" void kernel_launch(void* const* d_in, const int* in_sizes, int n_in,
                              void* d_out, int out_size, void* d_ws, size_t ws_size,
                              hipStream_t stream) {
  const float* cls    = (const float*)d_in[0];
  const float* bbox   = (const float*)d_in[1];
  const float* iminfo = (const float*)d_in[2];
  float* out = (float*)d_out;
  char* ws = (char*)d_ws;

  // ws layout. mask aliases u2 (u2 dead after k_compact; k_mask runs later).
  uint32_t* u2        = (uint32_t*)(ws + 0);            // NANCH u32 (18,874,368 B)
  uint64_t* mask      = (uint64_t*)(ws + 0);            // 94*6016 u64 (4,524,032 B)
  uint32_t* state     = (uint32_t*)(ws + 18874368);     // 256 B
  uint32_t* ghist0    = (uint32_t*)(ws + 18874624);     // 64 x 256 u32
  uint32_t* hist123   = (uint32_t*)(ws + 18940160);     // 3 x 256 u32
  uint32_t* sel_u     = (uint32_t*)(ws + 18943232);     // NPAD u32
  uint32_t* sel_idx   = (uint32_t*)(ws + 18967296);     // NPAD u32
  uint32_t* tie       = (uint32_t*)(ws + 18991360);     // TIECAP u32
  float*    sorted_sc = (float*)   (ws + 19007744);     // NPAD f32
  float4*   boxes     = (float4*)  (ws + 19031808);     // NPAD float4
  uint32_t* keepList  = (uint32_t*)(ws + 19128064);     // POSTN u32

  k_init<<<dim3(1), dim3(1024), 0, stream>>>(state, ghist0, hist123);
  k_score<<<dim3(NANCH/1024), dim3(256), 0, stream>>>(cls, bbox, iminfo, u2, ghist0);
  k_scan<<<dim3(1), dim3(256), 0, stream>>>(ghist0, state, 24, 64);
  k_hist<<<dim3(NANCH/1024), dim3(256), 0, stream>>>(u2, state, hist123, 16);
  k_scan<<<dim3(1), dim3(256), 0, stream>>>(hist123, state, 16, 1);
  k_hist<<<dim3(NANCH/1024), dim3(256), 0, stream>>>(u2, state, hist123 + 256, 8);
  k_scan<<<dim3(1), dim3(256), 0, stream>>>(hist123 + 256, state, 8, 1);
  k_hist<<<dim3(NANCH/1024), dim3(256), 0, stream>>>(u2, state, hist123 + 512, 0);
  k_scan<<<dim3(1), dim3(256), 0, stream>>>(hist123 + 512, state, 0, 1);
  k_compact<<<dim3(NANCH/1024), dim3(256), 0, stream>>>(u2, state, sel_u, sel_idx, tie);
  k_fin<<<dim3(1), dim3(1024), 0, stream>>>(state, sel_u, sel_idx, tie);
  k_rank<<<dim3(94), dim3(256), 0, stream>>>(sel_u, sel_idx, bbox, iminfo,
                                             sorted_sc, boxes);
  k_mask<<<dim3(NWORDS, NWORDS), dim3(64), 0, stream>>>(boxes, mask);
  k_nms<<<dim3(1), dim3(64), 0, stream>>>(mask, state, keepList);
  k_out<<<dim3(1), dim3(512), 0, stream>>>(state, keepList, boxes, sorted_sc, out);
}

// Round 11
// 435.514 us; speedup vs baseline: 1.7843x; 1.3287x over previous
//
#include <hip/hip_runtime.h>
#include <stdint.h>

#define FH 512
#define FW 768
#define HWSZ (FH*FW)           // 393216
#define NA 12
#define NANCH (HWSZ*NA)        // 4718592
#define KSEL 6000
#define NWORDS 94              // ceil(6000/64)
#define NPAD (NWORDS*64)       // 6016
#define ROWW 96                // padded words per mask row (row-major)
#define POSTN 300
#define TIECAP 4096
#define CAP 524288             // candidate buffer capacity

// 12 base anchors (ratios 0.5,1,2 x scales 4,8,16,32), precomputed from the
// reference generate_anchors(16,(0.5,1,2),(4,8,16,32)).
__constant__ float c_anch[12][4] = {
  {-38.f,-16.f,53.f,31.f},{-84.f,-40.f,99.f,55.f},{-176.f,-88.f,191.f,103.f},{-360.f,-184.f,375.f,199.f},
  {-24.f,-24.f,39.f,39.f},{-56.f,-56.f,71.f,71.f},{-120.f,-120.f,135.f,135.f},{-248.f,-248.f,263.f,263.f},
  {-14.f,-36.f,29.f,51.f},{-36.f,-80.f,51.f,95.f},{-80.f,-168.f,95.f,183.f},{-168.f,-344.f,183.f,359.f}
};

__device__ __forceinline__ uint32_t fsort(float f){
  uint32_t b = __float_as_uint(f);
  return (b & 0x80000000u) ? ~b : (b | 0x80000000u);
}
__device__ __forceinline__ float funsort(uint32_t u){
  uint32_t b = (u & 0x80000000u) ? (u & 0x7fffffffu) : ~u;
  return __uint_as_float(b);
}

// Clipped proposal box from loaded deltas. Plain (non-fma) fp32.
__device__ __forceinline__ float4 box_from(int a, int loc, float d0, float d1,
                                           float d2, float d3, float wlim, float hlim){
#pragma clang fp contract(off)
  int hh = loc / FW;
  int ww = loc - hh * FW;
  float sx = (float)ww * 16.0f, sy = (float)hh * 16.0f;
  float x1a = c_anch[a][0] + sx, y1a = c_anch[a][1] + sy;
  float x2a = c_anch[a][2] + sx, y2a = c_anch[a][3] + sy;
  float wa = x2a - x1a + 1.0f, ha = y2a - y1a + 1.0f;
  float cxa = x1a + 0.5f * wa, cya = y1a + 0.5f * ha;
  float pcx = d0 * wa + cxa;
  float pcy = d1 * ha + cya;
  float pw  = expf(d2) * wa;
  float ph  = expf(d3) * ha;
  float x1 = pcx - 0.5f * pw, y1 = pcy - 0.5f * ph;
  float x2 = pcx + 0.5f * pw, y2 = pcy + 0.5f * ph;
  x1 = fminf(fmaxf(x1, 0.0f), wlim);
  y1 = fminf(fmaxf(y1, 0.0f), hlim);
  x2 = fminf(fmaxf(x2, 0.0f), wlim);
  y2 = fminf(fmaxf(y2, 0.0f), hlim);
  return make_float4(x1, y1, x2, y2);
}

__device__ __forceinline__ float4 prop_box(int a, int loc, const float* __restrict__ bbox,
                                           float wlim, float hlim){
  size_t base = (size_t)(4*a) * HWSZ + (size_t)loc;
  float d0 = bbox[base];
  float d1 = bbox[base + (size_t)HWSZ];
  float d2 = bbox[base + (size_t)2*HWSZ];
  float d3 = bbox[base + (size_t)3*HWSZ];
  return box_from(a, loc, d0, d1, d2, d3, wlim, hlim);
}

// state words: 0=prefix/T 1=krem 4=keepCount 5=candCount
__global__ void k_init(uint32_t* __restrict__ state, uint32_t* __restrict__ ghist0,
                       uint32_t* __restrict__ ghist1, uint32_t* __restrict__ hist8){
  int t = threadIdx.x;
  for (int i = t; i < 64*256; i += 1024){ ghist0[i] = 0; ghist1[i] = 0; }
  for (int i = t; i < 256; i += 1024) hist8[i] = 0;
  if (t < 8) state[t] = (t == 1) ? (uint32_t)KSEL : 0u;
}

// 4 anchors/thread, float4 loads. Per-wave replicated LDS hist + 64-way
// replicated global hist (proven in r4: removed the 215us funnel).
__global__ __launch_bounds__(256) void k_score(const float* __restrict__ cls,
                        const float* __restrict__ bbox, const float* __restrict__ iminfo,
                        uint32_t* __restrict__ u2, uint32_t* __restrict__ ghist0){
  __shared__ uint32_t lh[4][256];
  for (int i = threadIdx.x; i < 1024; i += 256) ((uint32_t*)lh)[i] = 0;
  __syncthreads();
  int t = blockIdx.x * 256 + threadIdx.x;
  int p0 = t * 4;
  int a = p0 / HWSZ;                 // HWSZ % 4 == 0, so same a for all 4
  int loc0 = p0 - a * HWSZ;
  float him = iminfo[0], wim = iminfo[1], scale = iminfo[2];
  float ms = 16.0f * scale - 1.0f;
  float wlim = wim - 1.0f, hlim = him - 1.0f;
  size_t base = (size_t)(4*a) * HWSZ + (size_t)loc0;
  float4 d0 = *(const float4*)(bbox + base);
  float4 d1 = *(const float4*)(bbox + base + (size_t)HWSZ);
  float4 d2 = *(const float4*)(bbox + base + (size_t)2*HWSZ);
  float4 d3 = *(const float4*)(bbox + base + (size_t)3*HWSZ);
  float4 sc4 = *(const float4*)(cls + (size_t)(NA + a) * HWSZ + loc0);
  uint32_t u[4];
  const float dd0[4] = {d0.x, d0.y, d0.z, d0.w};
  const float dd1[4] = {d1.x, d1.y, d1.z, d1.w};
  const float dd2[4] = {d2.x, d2.y, d2.z, d2.w};
  const float dd3[4] = {d3.x, d3.y, d3.z, d3.w};
  const float ss[4]  = {sc4.x, sc4.y, sc4.z, sc4.w};
  int w = threadIdx.x >> 6;
#pragma unroll
  for (int j = 0; j < 4; ++j){
    float4 bx = box_from(a, loc0 + j, dd0[j], dd1[j], dd2[j], dd3[j], wlim, hlim);
    bool valid = (bx.z - bx.x >= ms) && (bx.w - bx.y >= ms);
    float m = valid ? ss[j] : -1e30f;
    u[j] = fsort(m);
    atomicAdd(&lh[w][u[j] >> 24], 1u);
  }
  *(uint4*)(u2 + p0) = make_uint4(u[0], u[1], u[2], u[3]);
  __syncthreads();
  int b = threadIdx.x;
  uint32_t v = lh[0][b] + lh[1][b] + lh[2][b] + lh[3][b];
  if (v) atomicAdd(&ghist0[(blockIdx.x & 63) * 256 + b], v);
}

// Pick bin: elements strictly above bin counted into krem bookkeeping.
__global__ void k_scan(const uint32_t* __restrict__ hist, uint32_t* __restrict__ state,
                       int shift, int reps){
  __shared__ uint32_t h[256];
  int t = threadIdx.x;
  uint32_t v = 0;
  for (int r = 0; r < reps; ++r) v += hist[r * 256 + t];
  h[t] = v;
  uint32_t k = state[1];
  __syncthreads();
  uint32_t cg = 0;
  for (int b = t + 1; b < 256; ++b) cg += h[b];
  if (cg < k && cg + h[t] >= k){
    state[0] = state[0] | (((uint32_t)t) << shift);
    state[1] = k - cg;
  }
}

// bits[23:16] histogram of elements whose top byte matches. 64-way replicated
// global merge (the r4 profile's hidden ~50us funnel: 2.36M matches -> 256 bins).
__global__ __launch_bounds__(256) void k_hist1(const uint32_t* __restrict__ u2,
                       const uint32_t* __restrict__ state, uint32_t* __restrict__ ghist1){
  __shared__ uint32_t lh[4][256];
  for (int i = threadIdx.x; i < 1024; i += 256) ((uint32_t*)lh)[i] = 0;
  __syncthreads();
  uint32_t B0 = state[0] >> 24;
  int p4 = blockIdx.x * 256 + threadIdx.x;
  uint4 uu = ((const uint4*)u2)[p4];
  uint32_t us[4] = {uu.x, uu.y, uu.z, uu.w};
  int w = threadIdx.x >> 6;
#pragma unroll
  for (int j = 0; j < 4; ++j){
    uint32_t u = us[j];
    if ((u >> 24) == B0) atomicAdd(&lh[w][(u >> 16) & 255u], 1u);
  }
  __syncthreads();
  int b = threadIdx.x;
  uint32_t v = lh[0][b] + lh[1][b] + lh[2][b] + lh[3][b];
  if (v) atomicAdd(&ghist1[(blockIdx.x & 63) * 256 + b], v);
}

// Compact all elements with (u>>16) >= P16 (~43k expected) into cand, and
// histogram bits[15:8] of the ==P16 ones. Kills two 19MB passes + 19MB compact.
__global__ __launch_bounds__(256) void k_histc(const uint32_t* __restrict__ u2,
                       uint32_t* __restrict__ state, uint32_t* __restrict__ hist8,
                       uint2* __restrict__ cand){
  __shared__ uint32_t lh[256];
  __shared__ uint32_t cnt, gbase;
  lh[threadIdx.x] = 0;
  if (threadIdx.x == 0) cnt = 0;
  __syncthreads();
  uint32_t P16 = state[0] >> 16;
  int p4 = blockIdx.x * 256 + threadIdx.x;
  uint4 uu = ((const uint4*)u2)[p4];
  uint32_t us[4] = {uu.x, uu.y, uu.z, uu.w};
  uint32_t myu[4], myn[4];
  int mycnt = 0;
#pragma unroll
  for (int j = 0; j < 4; ++j){
    uint32_t u = us[j];
    if ((u >> 16) >= P16){
      int p = p4 * 4 + j;
      int a = p / HWSZ;
      int loc = p - a * HWSZ;
      myu[mycnt] = u;
      myn[mycnt] = (uint32_t)loc * NA + (uint32_t)a;
      ++mycnt;
      if ((u >> 16) == P16) atomicAdd(&lh[(u >> 8) & 255u], 1u);
    }
  }
  uint32_t mypos = 0;
  if (mycnt) mypos = atomicAdd(&cnt, (uint32_t)mycnt);
  __syncthreads();
  if (threadIdx.x == 0 && cnt) gbase = atomicAdd(&state[5], cnt);
  __syncthreads();
  for (int j = 0; j < mycnt; ++j){
    uint32_t gp = gbase + mypos + (uint32_t)j;
    if (gp < (uint32_t)CAP) cand[gp] = make_uint2(myu[j], myn[j]);
  }
  uint32_t v = lh[threadIdx.x];
  if (v) atomicAdd(&hist8[threadIdx.x], v);
}

// Single block: final two 8-bit scans over the small candidate set, exact
// threshold T, compact sel/tie, tie sort by index, fill to 6000.
__global__ __launch_bounds__(1024) void k_small(const uint32_t* __restrict__ state,
        const uint32_t* __restrict__ hist8, const uint2* __restrict__ cand,
        uint32_t* __restrict__ sel_u, uint32_t* __restrict__ sel_idx,
        uint32_t* __restrict__ tie){
  __shared__ uint32_t h[256];
  __shared__ uint32_t tl[TIECAP];
  __shared__ uint32_t sh_pref, sh_krem, selc, tiec;
  int t = threadIdx.x;
  if (t == 0){ sh_pref = state[0]; sh_krem = state[1]; selc = 0; tiec = 0; }
  uint32_t Nc = state[5]; if (Nc > (uint32_t)CAP) Nc = CAP;
  if (t < 256) h[t] = hist8[t];
  __syncthreads();
  // scan A: bits[15:8]
  {
    uint32_t k = sh_krem, cg = 0, ht = (t < 256) ? h[t] : 0;
    if (t < 256) for (int b = t + 1; b < 256; ++b) cg += h[b];
    __syncthreads();
    if (t < 256 && cg < k && cg + ht >= k){ sh_pref |= ((uint32_t)t) << 8; sh_krem = k - cg; }
  }
  __syncthreads();
  uint32_t P24 = sh_pref >> 8;
  if (t < 256) h[t] = 0;
  __syncthreads();
  for (uint32_t i = t; i < Nc; i += 1024){
    uint2 c = cand[i];
    if ((c.x >> 8) == P24) atomicAdd(&h[c.x & 255u], 1u);
  }
  __syncthreads();
  // scan B: bits[7:0]
  {
    uint32_t k = sh_krem, cg = 0, ht = (t < 256) ? h[t] : 0;
    if (t < 256) for (int b = t + 1; b < 256; ++b) cg += h[b];
    __syncthreads();
    if (t < 256 && cg < k && cg + ht >= k){ sh_pref |= (uint32_t)t; sh_krem = k - cg; }
  }
  __syncthreads();
  uint32_t T = sh_pref;
  for (uint32_t i = t; i < Nc; i += 1024){
    uint2 c = cand[i];
    if (c.x > T){
      uint32_t pos = atomicAdd(&selc, 1u);
      if (pos < (uint32_t)KSEL){ sel_u[pos] = c.x; sel_idx[pos] = c.y; }
    } else if (c.x == T){
      uint32_t pos = atomicAdd(&tiec, 1u);
      if (pos < (uint32_t)TIECAP) tie[pos] = c.y;
    }
  }
  __syncthreads();
  uint32_t tieCount = tiec; if (tieCount > TIECAP) tieCount = TIECAP;
  uint32_t krem = sh_krem;
  uint32_t base = selc; if (base > (uint32_t)KSEL) base = KSEL;
  uint32_t m = 1; while (m < tieCount) m <<= 1;
  if (m > TIECAP) m = TIECAP;
  for (uint32_t i = t; i < m; i += 1024) tl[i] = (i < tieCount) ? tie[i] : 0xFFFFFFFFu;
  __syncthreads();
  for (uint32_t kk = 2; kk <= m; kk <<= 1){
    for (uint32_t j = kk >> 1; j > 0; j >>= 1){
      for (uint32_t i = t; i < m; i += 1024){
        uint32_t ixj = i ^ j;
        if (ixj > i){
          uint32_t x = tl[i], y = tl[ixj];
          bool up = ((i & kk) == 0);
          if ((x > y) == up){ tl[i] = y; tl[ixj] = x; }
        }
      }
      __syncthreads();
    }
  }
  uint32_t take = krem < tieCount ? krem : tieCount;
  if (base + take > (uint32_t)KSEL) take = KSEL - base;
  for (uint32_t i = t; i < take; i += 1024){ sel_u[base + i] = T; sel_idx[base + i] = tl[i]; }
  for (uint32_t i = base + take + t; i < (uint32_t)KSEL; i += 1024){
    sel_u[i] = 0u; sel_idx[i] = 0x7FFFFFFFu - i;
  }
}

// Rank each of 6000 by unique 64-bit key (score desc, index asc); 4 threads
// per element, b128 LDS reads. Scatter boxes/scores into sorted order.
__global__ __launch_bounds__(256) void k_rank(const uint32_t* __restrict__ sel_u,
                       const uint32_t* __restrict__ sel_idx,
                       const float* __restrict__ bbox, const float* __restrict__ iminfo,
                       float* __restrict__ sorted_sc, float4* __restrict__ boxes){
  __shared__ __align__(16) uint64_t keys[NPAD];
  __shared__ uint32_t part[256];
  for (int j = threadIdx.x; j < NPAD; j += 256)
    keys[j] = (j < KSEL) ? ((((uint64_t)sel_u[j]) << 32) | (uint32_t)(~sel_idx[j])) : 0ull;
  __syncthreads();
  int e = blockIdx.x * 64 + (threadIdx.x & 63);
  int q = threadIdx.x >> 6;
  uint64_t myk = (e < KSEL) ? keys[e] : ~0ull;
  int r = 0;
  int lo = q * (NPAD / 4);
#pragma unroll 2
  for (int j = lo; j < lo + NPAD / 4; j += 8){
    ulonglong2 k0 = *(const ulonglong2*)&keys[j];
    ulonglong2 k1 = *(const ulonglong2*)&keys[j + 2];
    ulonglong2 k2 = *(const ulonglong2*)&keys[j + 4];
    ulonglong2 k3 = *(const ulonglong2*)&keys[j + 6];
    r += (int)(k0.x > myk) + (int)(k0.y > myk) + (int)(k1.x > myk) + (int)(k1.y > myk)
       + (int)(k2.x > myk) + (int)(k2.y > myk) + (int)(k3.x > myk) + (int)(k3.y > myk);
  }
  part[threadIdx.x] = (uint32_t)r;
  __syncthreads();
  if (q == 0 && e < KSEL){
    int tt = threadIdx.x;
    int rr = (int)(part[tt] + part[tt + 64] + part[tt + 128] + part[tt + 192]);
    uint32_t idx = ~(uint32_t)myk;
    uint32_t u = (uint32_t)(myk >> 32);
    sorted_sc[rr] = funsort(u);
    int a = (int)(idx % NA);
    int loc = (int)(idx / NA);
    boxes[rr] = prop_box(a, loc, bbox, iminfo[1] - 1.0f, iminfo[0] - 1.0f);
  }
}

// Suppression bit matrix, ROW-major mask2[i*ROWW + w]: k_nms's kept-row gather
// becomes 2 coalesced lines per row instead of 128 scattered ones.
__global__ void k_mask(const float4* __restrict__ boxes, uint64_t* __restrict__ mask2){
#pragma clang fp contract(off)
  int tid = threadIdx.x;
  int cg = blockIdx.x, rg = blockIdx.y;
  __shared__ float4 cb[64];
  int c0 = cg * 64;
  int cj = c0 + tid;
  cb[tid] = (cj < KSEL) ? boxes[cj] : make_float4(0.f, 0.f, 0.f, 0.f);
  __syncthreads();
  int i = rg * 64 + tid;
  uint64_t m = 0;
  if (i < KSEL){
    float4 bi = boxes[i];
    float zx = bi.z + 1.0f, zy = bi.w + 1.0f;
    float ai = (zx - bi.x) * (zy - bi.y);
    int jmax = KSEL - c0; if (jmax > 64) jmax = 64;
    for (int jj = 0; jj < jmax; ++jj){
      int j = c0 + jj;
      if (j == i) continue;
      float4 bj = cb[jj];
      float jx = bj.z + 1.0f, jy = bj.w + 1.0f;
      float ww = fminf(zx, jx) - fmaxf(bi.x, bj.x); ww = fmaxf(ww, 0.0f);
      float hh = fminf(zy, jy) - fmaxf(bi.y, bj.y); hh = fmaxf(hh, 0.0f);
      float inter = ww * hh;
      float aj = (jx - bj.x) * (jy - bj.y);
      float iou = inter / (ai + aj - inter);
      if (iou > 0.7f) m |= (1ull << jj);
    }
  }
  mask2[(size_t)i * ROWW + cg] = m;
}

// Block-sequential greedy NMS, 1 wave. Within-block greedy is pure
// register/shuffle (iterates once per KEPT box, suppressed ones vanish via
// bit-ops); only kept rows (~300 total) are gathered (coalesced, row-major)
// and OR'd into the LDS suppression vector. No per-candidate LDS round-trip.
__global__ __launch_bounds__(64) void k_nms(const uint64_t* __restrict__ mask2,
                      uint32_t* __restrict__ state, uint32_t* __restrict__ keepList){
  __shared__ uint64_t sup[NWORDS];
  __shared__ uint64_t diag[NWORDS][64];
  int l = threadIdx.x;
  // prefetch all diagonal 64x64 bit-blocks (independent of sup chain)
  for (int b = 0; b < NWORDS; ++b)
    diag[b][l] = mask2[(size_t)(b * 64 + l) * ROWW + b];
  for (int w = l; w < NWORDS; w += 64) sup[w] = 0ull;
  __syncthreads();
  if (l == 0) sup[NWORDS - 1] = ~((1ull << (KSEL & 63)) - 1ull);  // pad bits
  __syncthreads();
  int cnt = 0;
  for (int b = 0; b < NWORDS && cnt < POSTN; ++b){
    uint64_t avail = ~sup[b];
    uint64_t d = diag[b][l];
    uint64_t kept = 0;
    int room = POSTN - cnt;
    while (avail && room){
      int tt = __ffsll((long long)avail) - 1;
      kept |= 1ull << tt;
      --room;
      uint64_t rowt = __shfl(d, tt, 64);          // uniform broadcast of row tt
      avail &= ~rowt & ~(1ull << tt);
    }
    // record kept indices (ascending within block = score order)
    if ((kept >> l) & 1ull){
      int r = __popcll(kept & ((1ull << l) - 1ull));
      keepList[cnt + r] = (uint32_t)(b * 64 + l);
    }
    // gather kept rows (coalesced: words l and 64+l consecutive across lanes)
    uint64_t mm = kept;
    uint64_t o0 = 0, o1 = 0;
    while (mm){
      int tt = __ffsll((long long)mm) - 1; mm &= mm - 1;
      size_t rb = (size_t)(b * 64 + tt) * ROWW;
      o0 |= mask2[rb + l];
      if (l + 64 < NWORDS) o1 |= mask2[rb + 64 + l];
    }
    cnt += __popcll(kept);
    __syncthreads();
    if (o0) sup[l] |= o0;
    if (o1) sup[64 + l] |= o1;
    __syncthreads();
  }
  if (l == 0) state[4] = (uint32_t)cnt;
}

__global__ void k_out(const uint32_t* __restrict__ state, const uint32_t* __restrict__ keepList,
                      const float4* __restrict__ boxes, const float* __restrict__ sorted_sc,
                      float* __restrict__ out){
  int r = blockIdx.x * blockDim.x + threadIdx.x;
  if (r >= POSTN) return;
  uint32_t cnt = state[4];
  float x1 = 0.f, y1 = 0.f, x2 = 0.f, y2 = 0.f, sc = 0.f;
  if (r < (int)cnt){
    int i = (int)keepList[r];
    float4 b = boxes[i];
    x1 = b.x; y1 = b.y; x2 = b.z; y2 = b.w;
    sc = sorted_sc[i];
  }
  out[r*5 + 0] = 0.f; out[r*5 + 1] = x1; out[r*5 + 2] = y1;
  out[r*5 + 3] = x2;  out[r*5 + 4] = y2;
  out[POSTN*5 + r] = sc;
}

extern "C" void kernel_launch(void* const* d_in, const int* in_sizes, int n_in,
                              void* d_out, int out_size, void* d_ws, size_t ws_size,
                              hipStream_t stream) {
  const float* cls    = (const float*)d_in[0];
  const float* bbox   = (const float*)d_in[1];
  const float* iminfo = (const float*)d_in[2];
  float* out = (float*)d_out;
  char* ws = (char*)d_ws;

  // ws layout (~23.4 MB). mask2 aliases u2 (u2 dead after k_histc).
  uint32_t* u2        = (uint32_t*)(ws + 0);            // NANCH u32 (18,874,368 B)
  uint64_t* mask2     = (uint64_t*)(ws + 0);            // NPAD*ROWW u64 (4,620,288 B)
  uint32_t* state     = (uint32_t*)(ws + 18874368);     // 256 B
  uint32_t* ghist0    = (uint32_t*)(ws + 18874624);     // 64*256 u32
  uint32_t* ghist1    = (uint32_t*)(ws + 18940160);     // 64*256 u32
  uint32_t* hist8     = (uint32_t*)(ws + 19005696);     // 256 u32 (pad to 1024B)
  uint32_t* sel_u     = (uint32_t*)(ws + 19006720);     // NPAD u32
  uint32_t* sel_idx   = (uint32_t*)(ws + 19030784);     // NPAD u32
  uint32_t* tie       = (uint32_t*)(ws + 19054848);     // TIECAP u32
  float*    sorted_sc = (float*)   (ws + 19071232);     // NPAD f32
  float4*   boxes     = (float4*)  (ws + 19095296);     // NPAD float4
  uint32_t* keepList  = (uint32_t*)(ws + 19191552);     // POSTN u32 (pad 1280B)
  uint2*    cand      = (uint2*)   (ws + 19192832);     // CAP uint2 (4,194,304 B)

  k_init<<<dim3(1), dim3(1024), 0, stream>>>(state, ghist0, ghist1, hist8);
  k_score<<<dim3(NANCH/1024), dim3(256), 0, stream>>>(cls, bbox, iminfo, u2, ghist0);
  k_scan<<<dim3(1), dim3(256), 0, stream>>>(ghist0, state, 24, 64);
  k_hist1<<<dim3(NANCH/1024), dim3(256), 0, stream>>>(u2, state, ghist1);
  k_scan<<<dim3(1), dim3(256), 0, stream>>>(ghist1, state, 16, 64);
  k_histc<<<dim3(NANCH/1024), dim3(256), 0, stream>>>(u2, state, hist8, cand);
  k_small<<<dim3(1), dim3(1024), 0, stream>>>(state, hist8, cand, sel_u, sel_idx, tie);
  k_rank<<<dim3(94), dim3(256), 0, stream>>>(sel_u, sel_idx, bbox, iminfo,
                                             sorted_sc, boxes);
  k_mask<<<dim3(NWORDS, NWORDS), dim3(64), 0, stream>>>(boxes, mask2);
  k_nms<<<dim3(1), dim3(64), 0, stream>>>(mask2, state, keepList);
  k_out<<<dim3(1), dim3(512), 0, stream>>>(state, keepList, boxes, sorted_sc, out);
}